// Round 1
// 461.991 us; speedup vs baseline: 1.0710x; 1.0710x over previous
//
#include <hip/hip_runtime.h>

#define B_   2
#define S_   2048
#define D_   2048
#define H_   16
#define HD_  128
#define WIN_ 256
#define M_   (B_ * S_)  // 4096

typedef float  f32x4  __attribute__((ext_vector_type(4)));
typedef short  s16x8  __attribute__((ext_vector_type(8)));
typedef __bf16 bf16x8 __attribute__((ext_vector_type(8)));
typedef unsigned short ushort_t;

__device__ inline unsigned short f2b(float f) {
  unsigned u = __builtin_bit_cast(unsigned, f);
  u += 0x7fffu + ((u >> 16) & 1u);  // RNE
  return (unsigned short)(u >> 16);
}
__device__ inline float b2f(unsigned short h) {
  unsigned u = ((unsigned)h) << 16;
  return __builtin_bit_cast(float, u);
}

// Hedged MFMA call: gfx950 builtin may take v8bf16 (upstream clang) or v8i16.
template <typename T>
__device__ auto mfma_impl(T a, T b, f32x4 c, int)
    -> decltype(__builtin_amdgcn_mfma_f32_16x16x32_bf16(a, b, c, 0, 0, 0)) {
  return __builtin_amdgcn_mfma_f32_16x16x32_bf16(a, b, c, 0, 0, 0);
}
template <typename T>
__device__ f32x4 mfma_impl(T a, T b, f32x4 c, long) {
  return __builtin_amdgcn_mfma_f32_16x16x32_bf16(
      __builtin_bit_cast(bf16x8, a), __builtin_bit_cast(bf16x8, b), c, 0, 0, 0);
}
__device__ inline f32x4 mfma_bf16(s16x8 a, s16x8 b, f32x4 c) {
  return mfma_impl(a, b, c, 0);
}

// ---- async global->LDS, 16B/lane. lds base must be wave-uniform; lane i lands at +i*16B.
#if defined(__has_builtin)
#if __has_builtin(__builtin_amdgcn_global_load_lds)
#define HAS_GLL 1
#endif
#endif
#ifndef HAS_GLL
#define HAS_GLL 0
#endif

__device__ inline void gl_lds16(const ushort_t* g, ushort_t* lds_wave_base) {
#if HAS_GLL
  __builtin_amdgcn_global_load_lds(
      (const __attribute__((address_space(1))) unsigned int*)g,
      (__attribute__((address_space(3))) unsigned int*)lds_wave_base, 16, 0, 0);
#else
  const int lane = threadIdx.x & 63;
  *(uint4*)(lds_wave_base + lane * 8) = *(const uint4*)g;
#endif
}

// ---------------- split f32 -> bf16 hi + lo ----------------
__global__ __launch_bounds__(256) void k_split(const float* __restrict__ x,
                                               ushort_t* __restrict__ hi,
                                               ushort_t* __restrict__ lo, int n) {
  int i = (blockIdx.x * 256 + threadIdx.x) * 4;
  if (i + 3 < n) {
    float4 v = *(const float4*)(x + i);
    ushort4 h, l;
    h.x = f2b(v.x); l.x = f2b(v.x - b2f(h.x));
    h.y = f2b(v.y); l.y = f2b(v.y - b2f(h.y));
    h.z = f2b(v.z); l.z = f2b(v.z - b2f(h.z));
    h.w = f2b(v.w); l.w = f2b(v.w - b2f(h.w));
    *(ushort4*)(hi + i) = h;
    *(ushort4*)(lo + i) = l;
  }
}

// ---------------- fused transpose + split of all 4 weights: z picks W ----------------
__global__ __launch_bounds__(256) void k_transpose4(const float* __restrict__ W0,
                                                    const float* __restrict__ W1,
                                                    const float* __restrict__ W2,
                                                    const float* __restrict__ W3,
                                                    ushort_t* __restrict__ T0h,
                                                    ushort_t* __restrict__ T0l,
                                                    ushort_t* __restrict__ T1h,
                                                    ushort_t* __restrict__ T1l,
                                                    ushort_t* __restrict__ T2h,
                                                    ushort_t* __restrict__ T3h) {
  __shared__ float t[32][33];
  const int z = blockIdx.z;
  const float* W = (z == 0) ? W0 : (z == 1) ? W1 : (z == 2) ? W2 : W3;
  ushort_t* Th = (z == 0) ? T0h : (z == 1) ? T1h : (z == 2) ? T2h : T3h;
  ushort_t* Tl = (z == 0) ? T0l : (z == 1) ? T1l : nullptr;
  int bx = blockIdx.x * 32, by = blockIdx.y * 32;
  int tx = threadIdx.x, ty = threadIdx.y;  // 32 x 8
#pragma unroll
  for (int r = 0; r < 32; r += 8)
    t[ty + r][tx] = W[(size_t)(by + ty + r) * D_ + bx + tx];
  __syncthreads();
#pragma unroll
  for (int r = 0; r < 32; r += 8) {
    float v = t[tx][ty + r];
    unsigned short h = f2b(v);
    Th[(size_t)(bx + ty + r) * D_ + by + tx] = h;
    if (Tl) Tl[(size_t)(bx + ty + r) * D_ + by + tx] = f2b(v - b2f(h));
  }
}

// ---------------- bf16 transpose for V: Vt[b*D + c][s] = Vb[b*S + s][c] ----------------
__global__ __launch_bounds__(256) void k_vtrans(const ushort_t* __restrict__ Vb,
                                                ushort_t* __restrict__ Vt) {
  __shared__ ushort_t t[32][33];
  int bx = blockIdx.x * 32, by = blockIdx.y * 32, b = blockIdx.z;
  int tx = threadIdx.x, ty = threadIdx.y;  // 32 x 8
#pragma unroll
  for (int r = 0; r < 32; r += 8)
    t[ty + r][tx] = Vb[((size_t)(b * S_ + by + ty + r)) * D_ + bx + tx];
  __syncthreads();
#pragma unroll
  for (int r = 0; r < 32; r += 8)
    Vt[((size_t)(b * D_ + bx + ty + r)) * S_ + by + tx] = t[tx][ty + r];
}

// ================= deep-pipelined MFMA GEMM: C = A[M x K*NSEG] * Bt[N x K*NSEG]^T ====
// Hi/lo split GEMMs expressed as K-concatenation over NSEG segments of K=2048:
//   NSEG=3 (Q): (Ah,Bh),(Al,Bh),(Ah,Bl)   NSEG=2 (K): (Ah,Bh),(Al,Bh)   NSEG=1: plain.
// BM=256 BN=128 BK=64. 512 thr = 8 waves (4M x 2N), per-wave 64x64 (4x4 16x16 frags).
// 3 rotating LDS buffers (144 KB): compute tile kt from buf[kt%3] while staging tile
// kt+2 into buf[(kt+2)%3] (freed at end of tile kt-1 -> provably race-free).
// Tile boundary waits are counted s_waitcnt vmcnt(6) (the 6 in-flight loads of tile
// kt+2) -- never drain-0 in steady state; raw s_barrier only (no __syncthreads).
// T2 swizzle: LDS 16B-slot s of row r holds global slot s^(r&7); applied by
// pre-swizzling the per-lane GLOBAL source addr (linear global_load_lds dest) and
// XOR-ing the ds_read addr. Removes the 16-way bank conflict of [*][64] bf16 rows.
// OUT: 0=bf16, 1=bf16 hi/lo, 2=f32+bias.

__device__ inline void stage_chunk(const ushort_t* __restrict__ gbase, int K,
                                   int rowbase, ushort_t* ldsTile, int tid) {
  const int rr = tid >> 3;                       // row within 64-row chunk
  const int gs = ((tid & 7) ^ (rr & 7)) * 8;     // swizzled source 16B-slot
  gl_lds16(gbase + (size_t)(rowbase + rr) * K + gs,
           ldsTile + rowbase * 64 + (tid >> 6) * 512);  // wave-uniform LDS base
}

template <int NSEG, int OUT>
__global__ __launch_bounds__(512) void k_gemm8(
    const ushort_t* __restrict__ A0, const ushort_t* __restrict__ A1,
    const ushort_t* __restrict__ A2, const ushort_t* __restrict__ B0,
    const ushort_t* __restrict__ B2, ushort_t* __restrict__ Co,
    ushort_t* __restrict__ Col, float* __restrict__ Cf,
    const float* __restrict__ bias, int M, int N, int K) {
  __shared__ ushort_t As_[3][256 * 64];  // 96 KB
  __shared__ ushort_t Bs_[3][128 * 64];  // 48 KB
  const int tid = threadIdx.x;
  const int wave = tid >> 6, lane = tid & 63;
  const int quad = lane >> 4, l16 = lane & 15;
  const int m0 = blockIdx.y * 256, n0 = blockIdx.x * 128;
  const int wrM = (wave >> 1) * 64;  // 0,64,128,192
  const int wcN = (wave & 1) * 64;   // 0,64
  const int aRowB = (wrM + l16) * 64;
  const int bRowB = (wcN + l16) * 64;
  int ks8[2];
  ks8[0] = ((0 + quad) ^ (l16 & 7)) * 8;  // ksub 0, swizzled slot
  ks8[1] = ((4 + quad) ^ (l16 & 7)) * 8;  // ksub 1
  const int NT = NSEG * 32;

  // ---- prologue: stage tiles 0 and 1 (always segment 0) ----
  {
    const ushort_t* Ab0 = A0 + (size_t)m0 * K;
    const ushort_t* Bb0 = B0 + (size_t)n0 * K;
#pragma unroll
    for (int t = 0; t < 2; ++t) {
      const ushort_t* Ab = Ab0 + t * 64;
      const ushort_t* Bb = Bb0 + t * 64;
      stage_chunk(Ab, K, 0,   &As_[t][0], tid);
      stage_chunk(Ab, K, 64,  &As_[t][0], tid);
      stage_chunk(Ab, K, 128, &As_[t][0], tid);
      stage_chunk(Ab, K, 192, &As_[t][0], tid);
      stage_chunk(Bb, K, 0,   &Bs_[t][0], tid);
      stage_chunk(Bb, K, 64,  &Bs_[t][0], tid);
    }
  }
  asm volatile("s_waitcnt vmcnt(6)" ::: "memory");  // tile 0 fully landed
  __builtin_amdgcn_s_barrier();
  asm volatile("" ::: "memory");

  f32x4 acc[4][4] = {};
  int cur = 0;  // kt % 3
  for (int kt = 0; kt < NT; ++kt) {
    const int st = kt + 2;
    const bool doStage = (st < NT);
    int sbuf = cur + 2; if (sbuf >= 3) sbuf -= 3;
    ushort_t* At  = &As_[cur][0];
    ushort_t* Bt  = &Bs_[cur][0];
    ushort_t* Ads = &As_[sbuf][0];
    ushort_t* Bds = &Bs_[sbuf][0];
    const ushort_t* Asb = A0;
    const ushort_t* Bsb = B0;
    if (doStage) {
      const int sg = st >> 5;
      const ushort_t* Ag = A0;
      const ushort_t* Bg = B0;
      if (NSEG >= 2 && sg == 1) Ag = A1;
      if (NSEG == 3 && sg == 2) { Ag = A2; Bg = B2; }
      Asb = Ag + (size_t)m0 * K + (size_t)(st & 31) * 64;
      Bsb = Bg + (size_t)n0 * K + (size_t)(st & 31) * 64;
    }
    s16x8 bf[4][2];
#pragma unroll
    for (int p = 0; p < 2; ++p) {
      // -- register subtile loads (swizzled ds_read_b128) --
      s16x8 af[2][2];
#pragma unroll
      for (int i = 0; i < 2; ++i)
#pragma unroll
        for (int s = 0; s < 2; ++s)
          af[i][s] = *(const s16x8*)(At + aRowB + (p * 2 + i) * 1024 + ks8[s]);
      if (p == 0) {
#pragma unroll
        for (int nt = 0; nt < 4; ++nt)
#pragma unroll
          for (int s = 0; s < 2; ++s)
            bf[nt][s] = *(const s16x8*)(Bt + bRowB + nt * 1024 + ks8[s]);
      }
      // -- issue staging for tile kt+2 (3 chunks per phase) --
      if (doStage) {
        if (p == 0) {
          stage_chunk(Asb, K, 0,   Ads, tid);
          stage_chunk(Asb, K, 64,  Ads, tid);
          stage_chunk(Asb, K, 128, Ads, tid);
        } else {
          stage_chunk(Asb, K, 192, Ads, tid);
          stage_chunk(Bsb, K, 0,   Bds, tid);
          stage_chunk(Bsb, K, 64,  Bds, tid);
        }
      }
      __builtin_amdgcn_s_barrier();
      asm volatile("s_waitcnt lgkmcnt(0)" ::: "memory");
      __builtin_amdgcn_sched_barrier(0);
      __builtin_amdgcn_s_setprio(1);
#pragma unroll
      for (int i = 0; i < 2; ++i)
#pragma unroll
        for (int nt = 0; nt < 4; ++nt)
#pragma unroll
          for (int s = 0; s < 2; ++s)
            acc[p * 2 + i][nt] = mfma_bf16(af[i][s], bf[nt][s], acc[p * 2 + i][nt]);
      __builtin_amdgcn_s_setprio(0);
      if (p == 1) {
        // tile boundary: everything older than tile kt+2's 6 loads must be done
        if (doStage) asm volatile("s_waitcnt vmcnt(6)" ::: "memory");
        else         asm volatile("s_waitcnt vmcnt(0)" ::: "memory");
      }
      __builtin_amdgcn_s_barrier();
      asm volatile("" ::: "memory");
    }
    cur = (cur == 2) ? 0 : cur + 1;
  }

  // ---- epilogue ----
#pragma unroll
  for (int mt = 0; mt < 4; ++mt)
#pragma unroll
    for (int nt = 0; nt < 4; ++nt)
#pragma unroll
      for (int r = 0; r < 4; ++r) {
        int row = m0 + wrM + mt * 16 + quad * 4 + r;
        int col = n0 + wcN + nt * 16 + l16;
        float v = acc[mt][nt][r];
        if (OUT == 2) {
          Cf[(size_t)row * N + col] = v + bias[col];
        } else if (OUT == 1) {
          unsigned short h = f2b(v);
          Co[(size_t)row * N + col]  = h;
          Col[(size_t)row * N + col] = f2b(v - b2f(h));
        } else {
          Co[(size_t)row * N + col] = f2b(v);
        }
      }
}

// ---------------- MFMA flash attention, 64-query tile per block ----------------
// Scores: split-2 bf16 QK^T: s = (qh+ql)·kh  (K-lo dropped; error ~0.02 on scores).
// P,V: plain bf16. Online softmax. R3-proven barrier structure — do not touch.
// grid: (S/64, H, B); 256 threads = 4 waves, wave w owns queries w*16..w*16+15.
__global__ __launch_bounds__(256) void k_fattn(const ushort_t* __restrict__ Qh,
                                               const ushort_t* __restrict__ Ql,
                                               const ushort_t* __restrict__ Kh,
                                               const ushort_t* __restrict__ Vt,
                                               const int* __restrict__ amask,
                                               ushort_t* __restrict__ AO) {
  __shared__ ushort_t Ksh[64][136];   // [key][dim], +8 pad (17.4 KB)
  __shared__ ushort_t Vs[128][72];    // [hd][key], +8 pad (18.4 KB)
  __shared__ ushort_t ps[4][16][72];  // per-wave P scratch [q][key] (9.2 KB)
  __shared__ int ams[320];            // total ~46.3 KB -> 3 blocks/CU
  const int tid = threadIdx.x;
  const int wave = tid >> 6, lane = tid & 63;
  const int quad = lane >> 4, l16 = lane & 15;
  const int qt = blockIdx.x, h = blockIdx.y, b = blockIdx.z;
  const int q0 = qt * 64;

  for (int x = tid; x < 320; x += 256) {
    int j = q0 - 256 + x;
    ams[x] = (j >= 0) ? amask[b * S_ + j] : 0;
  }

  const int qrowA = q0 + wave * 16 + l16;
  const ushort_t* qbh = Qh + ((size_t)(b * S_ + qrowA) * D_) + h * HD_;
  const ushort_t* qbl = Ql + ((size_t)(b * S_ + qrowA) * D_) + h * HD_;
  s16x8 qh[4], ql[4];
#pragma unroll
  for (int kk = 0; kk < 4; kk++) {
    qh[kk] = *(const s16x8*)(qbh + kk * 32 + quad * 8);
    ql[kk] = *(const s16x8*)(qbl + kk * 32 + quad * 8);
  }

  f32x4 O[8] = {};
  float m_run[4], l_run[4];
#pragma unroll
  for (int r = 0; r < 4; r++) { m_run[r] = -3.0e38f; l_run[r] = 0.f; }

  const int t0 = (qt < 4) ? (4 - qt) : 0;  // kb = 64*(qt+t-4) >= 0
  for (int t = t0; t < 5; t++) {
    const int kb = q0 - 256 + 64 * t;
    __syncthreads();
    // stage K tile (hi only): [key][dim]; thread: key=tid>>2, dims (tid&3)*32..+31
    {
      const int key = tid >> 2, dimb = (tid & 3) * 32;
      const ushort_t* kgh = Kh + ((size_t)(b * S_ + kb + key) * D_) + h * HD_ + dimb;
#pragma unroll
      for (int u = 0; u < 4; u++)
        *(uint4*)&Ksh[key][dimb + u * 8] = *(const uint4*)(kgh + u * 8);
      // stage V tile (pre-transposed): Vs[hd][key]; thread: hd=tid>>1, keys (tid&1)*32..+31
      const int hd = tid >> 1, keyb = (tid & 1) * 32;
      const ushort_t* vg = Vt + ((size_t)(b * D_ + h * HD_ + hd) * S_) + kb + keyb;
#pragma unroll
      for (int u = 0; u < 4; u++)
        *(uint4*)&Vs[hd][keyb + u * 8] = *(const uint4*)(vg + u * 8);
    }
    __syncthreads();

    f32x4 sacc[4] = {};
#pragma unroll
    for (int kk = 0; kk < 4; kk++)
#pragma unroll
      for (int nt = 0; nt < 4; nt++) {
        s16x8 kfh = *(const s16x8*)&Ksh[nt * 16 + l16][kk * 32 + quad * 8];
        sacc[nt] = mfma_bf16(qh[kk], kfh, sacc[nt]);
        sacc[nt] = mfma_bf16(ql[kk], kfh, sacc[nt]);
      }

#pragma unroll
    for (int nt = 0; nt < 4; nt++) {
      const int j = kb + nt * 16 + l16;
      const bool amok = ams[64 * t + nt * 16 + l16] != 0;
#pragma unroll
      for (int r = 0; r < 4; r++) {
        const int iq = q0 + wave * 16 + quad * 4 + r;
        const bool ok = amok && (j <= iq) && (j > iq - WIN_);
        if (!ok) sacc[nt][r] = -3.0e38f;
      }
    }
    float mt[4];
#pragma unroll
    for (int r = 0; r < 4; r++) {
      mt[r] = fmaxf(fmaxf(sacc[0][r], sacc[1][r]), fmaxf(sacc[2][r], sacc[3][r]));
      mt[r] = fmaxf(mt[r], __shfl_xor(mt[r], 1));
      mt[r] = fmaxf(mt[r], __shfl_xor(mt[r], 2));
      mt[r] = fmaxf(mt[r], __shfl_xor(mt[r], 4));
      mt[r] = fmaxf(mt[r], __shfl_xor(mt[r], 8));
    }
    float alpha[4], lt[4];
#pragma unroll
    for (int r = 0; r < 4; r++) {
      float mnew = fmaxf(m_run[r], mt[r]);
      alpha[r] = __expf(m_run[r] - mnew);
      m_run[r] = mnew;
      lt[r] = 0.f;
#pragma unroll
      for (int nt = 0; nt < 4; nt++) {
        float s = sacc[nt][r];
        float p = (s > -1.0e30f) ? __expf(s - mnew) : 0.f;
        sacc[nt][r] = p;
        lt[r] += p;
      }
      lt[r] += __shfl_xor(lt[r], 1);
      lt[r] += __shfl_xor(lt[r], 2);
      lt[r] += __shfl_xor(lt[r], 4);
      lt[r] += __shfl_xor(lt[r], 8);
      l_run[r] = l_run[r] * alpha[r] + lt[r];
    }
#pragma unroll
    for (int o = 0; o < 8; o++)
#pragma unroll
      for (int r = 0; r < 4; r++) O[o][r] *= alpha[r];
#pragma unroll
    for (int nt = 0; nt < 4; nt++)
#pragma unroll
      for (int r = 0; r < 4; r++)
        ps[wave][quad * 4 + r][nt * 16 + l16] = f2b(sacc[nt][r]);
    __syncthreads();
#pragma unroll
    for (int kk2 = 0; kk2 < 2; kk2++) {
      s16x8 pf = *(const s16x8*)&ps[wave][l16][kk2 * 32 + quad * 8];
#pragma unroll
      for (int o = 0; o < 8; o++) {
        s16x8 vf = *(const s16x8*)&Vs[o * 16 + l16][kk2 * 32 + quad * 8];
        O[o] = mfma_bf16(pf, vf, O[o]);
      }
    }
  }
#pragma unroll
  for (int r = 0; r < 4; r++) l_run[r] = 1.0f / l_run[r];
#pragma unroll
  for (int o = 0; o < 8; o++)
#pragma unroll
    for (int r = 0; r < 4; r++) {
      int row = q0 + wave * 16 + quad * 4 + r;
      AO[((size_t)(b * S_ + row) * D_) + h * HD_ + o * 16 + l16] = f2b(O[o][r] * l_run[r]);
    }
}

extern "C" void kernel_launch(void* const* d_in, const int* in_sizes, int n_in,
                              void* d_out, int out_size, void* d_ws, size_t ws_size,
                              hipStream_t stream) {
  const float* hs    = (const float*)d_in[0];
  const int*   amask = (const int*)d_in[1];
  const float* Wq    = (const float*)d_in[2];
  const float* Wk    = (const float*)d_in[3];
  const float* Wv    = (const float*)d_in[4];
  const float* Wo    = (const float*)d_in[5];
  const float* bo    = (const float*)d_in[6];
  float* out = (float*)d_out;

  // workspace layout; hsHi reused as AO after V-GEMM. (WkTl slot retained but unused.)
  char* p = (char*)d_ws;
  ushort_t* hsHi = (ushort_t*)p; p += (size_t)16 << 20;
  ushort_t* hsLo = (ushort_t*)p; p += (size_t)16 << 20;
  ushort_t* WqTh = (ushort_t*)p; p += (size_t)8 << 20;
  ushort_t* WqTl = (ushort_t*)p; p += (size_t)8 << 20;
  ushort_t* WkTh = (ushort_t*)p; p += (size_t)8 << 20;
  ushort_t* WkTl = (ushort_t*)p; p += (size_t)8 << 20;  (void)WkTl;
  ushort_t* WvTh = (ushort_t*)p; p += (size_t)8 << 20;
  ushort_t* WoTh = (ushort_t*)p; p += (size_t)8 << 20;
  ushort_t* Qhb  = (ushort_t*)p; p += (size_t)16 << 20;
  ushort_t* Qlb  = (ushort_t*)p; p += (size_t)16 << 20;
  ushort_t* Khb  = (ushort_t*)p; p += (size_t)16 << 20;
  ushort_t* Vb   = (ushort_t*)p; p += (size_t)16 << 20;
  ushort_t* Vt   = (ushort_t*)p; p += (size_t)16 << 20;

  k_split<<<M_ * D_ / 1024, 256, 0, stream>>>(hs, hsHi, hsLo, M_ * D_);
  dim3 tb(32, 8), tg4(D_ / 32, D_ / 32, 4);
  k_transpose4<<<tg4, tb, 0, stream>>>(Wq, Wk, Wv, Wo, WqTh, WqTl, WkTh, nullptr, WvTh, WoTh);

  dim3 g8(D_ / 128, M_ / 256);  // (16, 16) = 256 wgs, 512 thr
  // Q: split-3 = K-concat segs (Ah,Bh),(Al,Bh),(Ah,Bl)
  k_gemm8<3, 1><<<g8, 512, 0, stream>>>(hsHi, hsLo, hsHi, WqTh, WqTl,
                                        Qhb, Qlb, nullptr, nullptr, M_, D_, D_);
  // K: split-2 = (Ah,Bh),(Al,Bh)
  k_gemm8<2, 0><<<g8, 512, 0, stream>>>(hsHi, hsLo, nullptr, WkTh, nullptr,
                                        Khb, nullptr, nullptr, nullptr, M_, D_, D_);
  // V: plain
  k_gemm8<1, 0><<<g8, 512, 0, stream>>>(hsHi, nullptr, nullptr, WvTh, nullptr,
                                        Vb, nullptr, nullptr, nullptr, M_, D_, D_);

  dim3 vg(D_ / 32, S_ / 32, B_);
  k_vtrans<<<vg, tb, 0, stream>>>(Vb, Vt);

  dim3 ag(S_ / 64, H_, B_);  // (32, 16, 2)
  k_fattn<<<ag, 256, 0, stream>>>(Qhb, Qlb, Khb, Vt, amask, hsHi /*AO*/);

  // O: plain, f32 + bias epilogue
  k_gemm8<1, 2><<<g8, 512, 0, stream>>>(hsHi /*AO*/, nullptr, nullptr, WoTh, nullptr,
                                        nullptr, nullptr, out, bo, M_, D_, D_);
}

// Round 3
// 441.266 us; speedup vs baseline: 1.1213x; 1.0470x over previous
//
#include <hip/hip_runtime.h>

#define B_   2
#define S_   2048
#define D_   2048
#define H_   16
#define HD_  128
#define WIN_ 256
#define M_   (B_ * S_)  // 4096

typedef float  f32x4  __attribute__((ext_vector_type(4)));
typedef short  s16x8  __attribute__((ext_vector_type(8)));
typedef __bf16 bf16x8 __attribute__((ext_vector_type(8)));
typedef unsigned short ushort_t;

__device__ inline unsigned short f2b(float f) {
  unsigned u = __builtin_bit_cast(unsigned, f);
  u += 0x7fffu + ((u >> 16) & 1u);  // RNE
  return (unsigned short)(u >> 16);
}
__device__ inline float b2f(unsigned short h) {
  unsigned u = ((unsigned)h) << 16;
  return __builtin_bit_cast(float, u);
}

// Hedged MFMA call: gfx950 builtin may take v8bf16 (upstream clang) or v8i16.
template <typename T>
__device__ auto mfma_impl(T a, T b, f32x4 c, int)
    -> decltype(__builtin_amdgcn_mfma_f32_16x16x32_bf16(a, b, c, 0, 0, 0)) {
  return __builtin_amdgcn_mfma_f32_16x16x32_bf16(a, b, c, 0, 0, 0);
}
template <typename T>
__device__ f32x4 mfma_impl(T a, T b, f32x4 c, long) {
  return __builtin_amdgcn_mfma_f32_16x16x32_bf16(
      __builtin_bit_cast(bf16x8, a), __builtin_bit_cast(bf16x8, b), c, 0, 0, 0);
}
__device__ inline f32x4 mfma_bf16(s16x8 a, s16x8 b, f32x4 c) {
  return mfma_impl(a, b, c, 0);
}

// ---- async global->LDS, 16B/lane. lds base must be wave-uniform; lane i lands at +i*16B.
#if defined(__has_builtin)
#if __has_builtin(__builtin_amdgcn_global_load_lds)
#define HAS_GLL 1
#endif
#endif
#ifndef HAS_GLL
#define HAS_GLL 0
#endif

__device__ inline void gl_lds16(const ushort_t* g, ushort_t* lds_wave_base) {
#if HAS_GLL
  __builtin_amdgcn_global_load_lds(
      (const __attribute__((address_space(1))) unsigned int*)g,
      (__attribute__((address_space(3))) unsigned int*)lds_wave_base, 16, 0, 0);
#else
  const int lane = threadIdx.x & 63;
  *(uint4*)(lds_wave_base + lane * 8) = *(const uint4*)g;
#endif
}

// ---------------- split f32 -> bf16 hi + lo ----------------
__global__ __launch_bounds__(256) void k_split(const float* __restrict__ x,
                                               ushort_t* __restrict__ hi,
                                               ushort_t* __restrict__ lo, int n) {
  int i = (blockIdx.x * 256 + threadIdx.x) * 4;
  if (i + 3 < n) {
    float4 v = *(const float4*)(x + i);
    ushort4 h, l;
    h.x = f2b(v.x); l.x = f2b(v.x - b2f(h.x));
    h.y = f2b(v.y); l.y = f2b(v.y - b2f(h.y));
    h.z = f2b(v.z); l.z = f2b(v.z - b2f(h.z));
    h.w = f2b(v.w); l.w = f2b(v.w - b2f(h.w));
    *(ushort4*)(hi + i) = h;
    *(ushort4*)(lo + i) = l;
  }
}

// ---------------- fused transpose + split of all 4 weights: z picks W ----------------
__global__ __launch_bounds__(256) void k_transpose4(const float* __restrict__ W0,
                                                    const float* __restrict__ W1,
                                                    const float* __restrict__ W2,
                                                    const float* __restrict__ W3,
                                                    ushort_t* __restrict__ T0h,
                                                    ushort_t* __restrict__ T0l,
                                                    ushort_t* __restrict__ T1h,
                                                    ushort_t* __restrict__ T1l,
                                                    ushort_t* __restrict__ T2h,
                                                    ushort_t* __restrict__ T3h) {
  __shared__ float t[32][33];
  const int z = blockIdx.z;
  const float* W = (z == 0) ? W0 : (z == 1) ? W1 : (z == 2) ? W2 : W3;
  ushort_t* Th = (z == 0) ? T0h : (z == 1) ? T1h : (z == 2) ? T2h : T3h;
  ushort_t* Tl = (z == 0) ? T0l : (z == 1) ? T1l : nullptr;
  int bx = blockIdx.x * 32, by = blockIdx.y * 32;
  int tx = threadIdx.x, ty = threadIdx.y;  // 32 x 8
#pragma unroll
  for (int r = 0; r < 32; r += 8)
    t[ty + r][tx] = W[(size_t)(by + ty + r) * D_ + bx + tx];
  __syncthreads();
#pragma unroll
  for (int r = 0; r < 32; r += 8) {
    float v = t[tx][ty + r];
    unsigned short h = f2b(v);
    Th[(size_t)(bx + ty + r) * D_ + by + tx] = h;
    if (Tl) Tl[(size_t)(bx + ty + r) * D_ + by + tx] = f2b(v - b2f(h));
  }
}

// ---------------- bf16 transpose for V: Vt[b*D + c][s] = Vb[b*S + s][c] ----------------
__global__ __launch_bounds__(256) void k_vtrans(const ushort_t* __restrict__ Vb,
                                                ushort_t* __restrict__ Vt) {
  __shared__ ushort_t t[32][33];
  int bx = blockIdx.x * 32, by = blockIdx.y * 32, b = blockIdx.z;
  int tx = threadIdx.x, ty = threadIdx.y;  // 32 x 8
#pragma unroll
  for (int r = 0; r < 32; r += 8)
    t[ty + r][tx] = Vb[((size_t)(b * S_ + by + ty + r)) * D_ + bx + tx];
  __syncthreads();
#pragma unroll
  for (int r = 0; r < 32; r += 8)
    Vt[((size_t)(b * D_ + bx + ty + r)) * S_ + by + tx] = t[tx][ty + r];
}

// ================= fused QKV GEMM: C = A[4096 x 2048*segs] * [Wq|Wk|Wv]^T =========
// 256x256 tile, BK=32, 512 thr = 8 waves (2M x 4N) -> per-wave 128x64 output
// (2.67 MFMA per ds_read_b128 -- the m201 ratio; fixes R1's LDS-read starvation).
// 4 rotating LDS buffers (128 KB): compute tile kt from buf[kt&3], stage tile kt+3
// into buf[(kt+3)&3] -- never the current/next/next-next buffer => race-free.
// 3-tile prefetch lead (~930 cyc) covers HBM latency. Tile-boundary wait:
// s_waitcnt vmcnt(8) (tiles kt+2,kt+3 = 8 loads in flight); never drain-0 mid-loop.
// Swizzle for 64B rows: 16B-slot s of row r holds global slot s^((r>>1)&3);
// per quarter-wave b128 read this spreads 16 rows over 8 16B-columns (2-way, free).
// N-concat: bx<8 -> Q (3 K-segments: (Ah,Wh),(Al,Wh),(Ah,Wl)); bx<16 -> K (2 segs);
// else V (1 seg). Block remap groups each XCD onto 2 contiguous M-panels.

__device__ inline void stage32(const ushort_t* __restrict__ g, int rowbase,
                               ushort_t* ldsTile, int tid) {
  const int rr = tid >> 2;                               // row 0..127 in chunk
  const int gs = ((tid & 3) ^ ((rr >> 1) & 3)) * 8;      // swizzled source slot
  gl_lds16(g + (size_t)(rowbase + rr) * D_ + gs,
           ldsTile + rowbase * 32 + (tid >> 6) * 512);   // wave-uniform LDS base
}

__global__ __launch_bounds__(512) void k_qkv(
    const ushort_t* __restrict__ Ah, const ushort_t* __restrict__ Al,
    const ushort_t* __restrict__ WqH, const ushort_t* __restrict__ WqL,
    const ushort_t* __restrict__ WkH, const ushort_t* __restrict__ WvH,
    ushort_t* __restrict__ Qh, ushort_t* __restrict__ Ql,
    ushort_t* __restrict__ Ko, ushort_t* __restrict__ Vo) {
  __shared__ ushort_t As_[4][256 * 32];  // 64 KB
  __shared__ ushort_t Bs_[4][256 * 32];  // 64 KB
  const int tid = threadIdx.x;
  const int wave = tid >> 6, lane = tid & 63;
  const int quad = lane >> 4, l16 = lane & 15;

  // bijective remap: XCD g (= orig linear id % 8) owns new ids g*48..g*48+47
  // = 2 contiguous M-panels -> A fetched ~once per XCD, L2-resident.
  const int lid = blockIdx.y * 24 + blockIdx.x;
  const int nlid = (lid & 7) * 48 + (lid >> 3);
  const int bx = nlid % 24, by = nlid / 24;
  const int m0 = by * 256;
  const int wtype = bx >> 3;            // 0=Q 1=K 2=V
  const int n0 = (bx & 7) * 256;
  const int nseg = (wtype == 0) ? 3 : (wtype == 1) ? 2 : 1;
  const ushort_t* Bh0 = (wtype == 0) ? WqH : (wtype == 1) ? WkH : WvH;
  const int NT = nseg << 6;             // K-tiles of 32

  const int wrM = (wave >> 2) * 128;    // 0 or 128
  const int wcN = (wave & 3) * 64;      // 0,64,128,192
  const int koff = (quad ^ ((l16 >> 1) & 3)) * 8;  // per-thread constant read slot

  // ---- prologue: stage tiles 0,1,2 (segment 0) ----
  {
    const ushort_t* Ap = Ah + (size_t)m0 * D_;
    const ushort_t* Bp = Bh0 + (size_t)n0 * D_;
#pragma unroll
    for (int t = 0; t < 3; ++t) {
      stage32(Ap + t * 32, 0,   &As_[t][0], tid);
      stage32(Ap + t * 32, 128, &As_[t][0], tid);
      stage32(Bp + t * 32, 0,   &Bs_[t][0], tid);
      stage32(Bp + t * 32, 128, &Bs_[t][0], tid);
    }
  }
  asm volatile("s_waitcnt vmcnt(8)" ::: "memory");  // tile 0 landed
  __builtin_amdgcn_s_barrier();
  asm volatile("" ::: "memory");

  f32x4 acc[8][4] = {};
  for (int kt = 0; kt < NT; ++kt) {
    const int st = kt + 3;
    const bool doSt = (st < NT);
    const int cur = kt & 3, sb = st & 3;
    const ushort_t* At = &As_[cur][0];
    const ushort_t* Bt = &Bs_[cur][0];
    ushort_t* Ad = &As_[sb][0];
    ushort_t* Bd = &Bs_[sb][0];
    const ushort_t* Asrc = Ah;
    const ushort_t* Bsrc = Bh0;
    if (doSt) {
      const int sg = st >> 6, so = (st & 63) * 32;
      const ushort_t* Ab = (sg == 1) ? Al : Ah;          // segs: Ah, Al, Ah
      const ushort_t* Bb = (sg == 2) ? WqL : Bh0;        // segs: Wh, Wh, Wl(Q only)
      Asrc = Ab + (size_t)m0 * D_ + so;
      Bsrc = Bb + (size_t)n0 * D_ + so;
    }
    s16x8 bf[4];
    // ---------- phase 0: rows wrM..wrM+63 ----------
    {
      s16x8 af[4];
#pragma unroll
      for (int mt = 0; mt < 4; ++mt)
        af[mt] = *(const s16x8*)(At + (wrM + mt * 16 + l16) * 32 + koff);
#pragma unroll
      for (int nt = 0; nt < 4; ++nt)
        bf[nt] = *(const s16x8*)(Bt + (wcN + nt * 16 + l16) * 32 + koff);
      if (doSt) {
        stage32(Asrc, 0,   Ad, tid);
        stage32(Asrc, 128, Ad, tid);
      }
      __builtin_amdgcn_s_barrier();
      asm volatile("s_waitcnt lgkmcnt(0)" ::: "memory");
      __builtin_amdgcn_sched_barrier(0);
      __builtin_amdgcn_s_setprio(1);
#pragma unroll
      for (int mt = 0; mt < 4; ++mt)
#pragma unroll
        for (int nt = 0; nt < 4; ++nt)
          acc[mt][nt] = mfma_bf16(af[mt], bf[nt], acc[mt][nt]);
      __builtin_amdgcn_s_setprio(0);
      __builtin_amdgcn_s_barrier();
      asm volatile("" ::: "memory");
    }
    // ---------- phase 1: rows wrM+64..wrM+127 ----------
    {
      s16x8 af[4];
#pragma unroll
      for (int mt = 0; mt < 4; ++mt)
        af[mt] = *(const s16x8*)(At + (wrM + 64 + mt * 16 + l16) * 32 + koff);
      if (doSt) {
        stage32(Bsrc, 0,   Bd, tid);
        stage32(Bsrc, 128, Bd, tid);
      }
      __builtin_amdgcn_s_barrier();
      asm volatile("s_waitcnt lgkmcnt(0)" ::: "memory");
      __builtin_amdgcn_sched_barrier(0);
      __builtin_amdgcn_s_setprio(1);
#pragma unroll
      for (int mt = 0; mt < 4; ++mt)
#pragma unroll
        for (int nt = 0; nt < 4; ++nt)
          acc[4 + mt][nt] = mfma_bf16(af[mt], bf[nt], acc[4 + mt][nt]);
      __builtin_amdgcn_s_setprio(0);
      if (doSt)              asm volatile("s_waitcnt vmcnt(8)" ::: "memory");
      else if (kt == NT - 3) asm volatile("s_waitcnt vmcnt(4)" ::: "memory");
      else if (kt == NT - 2) asm volatile("s_waitcnt vmcnt(0)" ::: "memory");
      __builtin_amdgcn_s_barrier();
      asm volatile("" ::: "memory");
    }
  }

  // ---- epilogue: wave writes its 128x64 sub-tile ----
#pragma unroll
  for (int a = 0; a < 8; ++a)
#pragma unroll
    for (int nt = 0; nt < 4; ++nt)
#pragma unroll
      for (int r = 0; r < 4; ++r) {
        const int row = m0 + wrM + a * 16 + quad * 4 + r;
        const int col = n0 + wcN + nt * 16 + l16;
        const float v = acc[a][nt][r];
        const size_t idx = (size_t)row * D_ + col;
        if (wtype == 0) {
          unsigned short h = f2b(v);
          Qh[idx] = h;
          Ql[idx] = f2b(v - b2f(h));
        } else if (wtype == 1) {
          Ko[idx] = f2b(v);
        } else {
          Vo[idx] = f2b(v);
        }
      }
}

// ================= R1 GEMM (kept for the O-projection) ====================
__device__ inline void stage_chunk(const ushort_t* __restrict__ gbase, int K,
                                   int rowbase, ushort_t* ldsTile, int tid) {
  const int rr = tid >> 3;                       // row within 64-row chunk
  const int gs = ((tid & 7) ^ (rr & 7)) * 8;     // swizzled source 16B-slot
  gl_lds16(gbase + (size_t)(rowbase + rr) * K + gs,
           ldsTile + rowbase * 64 + (tid >> 6) * 512);  // wave-uniform LDS base
}

template <int NSEG, int OUT>
__global__ __launch_bounds__(512) void k_gemm8(
    const ushort_t* __restrict__ A0, const ushort_t* __restrict__ A1,
    const ushort_t* __restrict__ A2, const ushort_t* __restrict__ B0,
    const ushort_t* __restrict__ B2, ushort_t* __restrict__ Co,
    ushort_t* __restrict__ Col, float* __restrict__ Cf,
    const float* __restrict__ bias, int M, int N, int K) {
  __shared__ ushort_t As_[3][256 * 64];  // 96 KB
  __shared__ ushort_t Bs_[3][128 * 64];  // 48 KB
  const int tid = threadIdx.x;
  const int wave = tid >> 6, lane = tid & 63;
  const int quad = lane >> 4, l16 = lane & 15;
  const int m0 = blockIdx.y * 256, n0 = blockIdx.x * 128;
  const int wrM = (wave >> 1) * 64;  // 0,64,128,192
  const int wcN = (wave & 1) * 64;   // 0,64
  const int aRowB = (wrM + l16) * 64;
  const int bRowB = (wcN + l16) * 64;
  int ks8[2];
  ks8[0] = ((0 + quad) ^ (l16 & 7)) * 8;
  ks8[1] = ((4 + quad) ^ (l16 & 7)) * 8;
  const int NT = NSEG * 32;

  {
    const ushort_t* Ab0 = A0 + (size_t)m0 * K;
    const ushort_t* Bb0 = B0 + (size_t)n0 * K;
#pragma unroll
    for (int t = 0; t < 2; ++t) {
      const ushort_t* Ab = Ab0 + t * 64;
      const ushort_t* Bb = Bb0 + t * 64;
      stage_chunk(Ab, K, 0,   &As_[t][0], tid);
      stage_chunk(Ab, K, 64,  &As_[t][0], tid);
      stage_chunk(Ab, K, 128, &As_[t][0], tid);
      stage_chunk(Ab, K, 192, &As_[t][0], tid);
      stage_chunk(Bb, K, 0,   &Bs_[t][0], tid);
      stage_chunk(Bb, K, 64,  &Bs_[t][0], tid);
    }
  }
  asm volatile("s_waitcnt vmcnt(6)" ::: "memory");
  __builtin_amdgcn_s_barrier();
  asm volatile("" ::: "memory");

  f32x4 acc[4][4] = {};
  int cur = 0;
  for (int kt = 0; kt < NT; ++kt) {
    const int st = kt + 2;
    const bool doStage = (st < NT);
    int sbuf = cur + 2; if (sbuf >= 3) sbuf -= 3;
    ushort_t* At  = &As_[cur][0];
    ushort_t* Bt  = &Bs_[cur][0];
    ushort_t* Ads = &As_[sbuf][0];
    ushort_t* Bds = &Bs_[sbuf][0];
    const ushort_t* Asb = A0;
    const ushort_t* Bsb = B0;
    if (doStage) {
      const int sg = st >> 5;
      const ushort_t* Ag = A0;
      const ushort_t* Bg = B0;
      if (NSEG >= 2 && sg == 1) Ag = A1;
      if (NSEG == 3 && sg == 2) { Ag = A2; Bg = B2; }
      Asb = Ag + (size_t)m0 * K + (size_t)(st & 31) * 64;
      Bsb = Bg + (size_t)n0 * K + (size_t)(st & 31) * 64;
    }
    s16x8 bf[4][2];
#pragma unroll
    for (int p = 0; p < 2; ++p) {
      s16x8 af[2][2];
#pragma unroll
      for (int i = 0; i < 2; ++i)
#pragma unroll
        for (int s = 0; s < 2; ++s)
          af[i][s] = *(const s16x8*)(At + aRowB + (p * 2 + i) * 1024 + ks8[s]);
      if (p == 0) {
#pragma unroll
        for (int nt = 0; nt < 4; ++nt)
#pragma unroll
          for (int s = 0; s < 2; ++s)
            bf[nt][s] = *(const s16x8*)(Bt + bRowB + nt * 1024 + ks8[s]);
      }
      if (doStage) {
        if (p == 0) {
          stage_chunk(Asb, K, 0,   Ads, tid);
          stage_chunk(Asb, K, 64,  Ads, tid);
          stage_chunk(Asb, K, 128, Ads, tid);
        } else {
          stage_chunk(Asb, K, 192, Ads, tid);
          stage_chunk(Bsb, K, 0,   Bds, tid);
          stage_chunk(Bsb, K, 64,  Bds, tid);
        }
      }
      __builtin_amdgcn_s_barrier();
      asm volatile("s_waitcnt lgkmcnt(0)" ::: "memory");
      __builtin_amdgcn_sched_barrier(0);
      __builtin_amdgcn_s_setprio(1);
#pragma unroll
      for (int i = 0; i < 2; ++i)
#pragma unroll
        for (int nt = 0; nt < 4; ++nt)
#pragma unroll
          for (int s = 0; s < 2; ++s)
            acc[p * 2 + i][nt] = mfma_bf16(af[i][s], bf[nt][s], acc[p * 2 + i][nt]);
      __builtin_amdgcn_s_setprio(0);
      if (p == 1) {
        if (doStage) asm volatile("s_waitcnt vmcnt(6)" ::: "memory");
        else         asm volatile("s_waitcnt vmcnt(0)" ::: "memory");
      }
      __builtin_amdgcn_s_barrier();
      asm volatile("" ::: "memory");
    }
    cur = (cur == 2) ? 0 : cur + 1;
  }

#pragma unroll
  for (int mt = 0; mt < 4; ++mt)
#pragma unroll
    for (int nt = 0; nt < 4; ++nt)
#pragma unroll
      for (int r = 0; r < 4; ++r) {
        int row = m0 + wrM + mt * 16 + quad * 4 + r;
        int col = n0 + wcN + nt * 16 + l16;
        float v = acc[mt][nt][r];
        if (OUT == 2) {
          Cf[(size_t)row * N + col] = v + bias[col];
        } else if (OUT == 1) {
          unsigned short h = f2b(v);
          Co[(size_t)row * N + col]  = h;
          Col[(size_t)row * N + col] = f2b(v - b2f(h));
        } else {
          Co[(size_t)row * N + col] = f2b(v);
        }
      }
}

// ---------------- MFMA flash attention, 64-query tile per block ----------------
__global__ __launch_bounds__(256) void k_fattn(const ushort_t* __restrict__ Qh,
                                               const ushort_t* __restrict__ Ql,
                                               const ushort_t* __restrict__ Kh,
                                               const ushort_t* __restrict__ Vt,
                                               const int* __restrict__ amask,
                                               ushort_t* __restrict__ AO) {
  __shared__ ushort_t Ksh[64][136];
  __shared__ ushort_t Vs[128][72];
  __shared__ ushort_t ps[4][16][72];
  __shared__ int ams[320];
  const int tid = threadIdx.x;
  const int wave = tid >> 6, lane = tid & 63;
  const int quad = lane >> 4, l16 = lane & 15;
  const int qt = blockIdx.x, h = blockIdx.y, b = blockIdx.z;
  const int q0 = qt * 64;

  for (int x = tid; x < 320; x += 256) {
    int j = q0 - 256 + x;
    ams[x] = (j >= 0) ? amask[b * S_ + j] : 0;
  }

  const int qrowA = q0 + wave * 16 + l16;
  const ushort_t* qbh = Qh + ((size_t)(b * S_ + qrowA) * D_) + h * HD_;
  const ushort_t* qbl = Ql + ((size_t)(b * S_ + qrowA) * D_) + h * HD_;
  s16x8 qh[4], ql[4];
#pragma unroll
  for (int kk = 0; kk < 4; kk++) {
    qh[kk] = *(const s16x8*)(qbh + kk * 32 + quad * 8);
    ql[kk] = *(const s16x8*)(qbl + kk * 32 + quad * 8);
  }

  f32x4 O[8] = {};
  float m_run[4], l_run[4];
#pragma unroll
  for (int r = 0; r < 4; r++) { m_run[r] = -3.0e38f; l_run[r] = 0.f; }

  const int t0 = (qt < 4) ? (4 - qt) : 0;
  for (int t = t0; t < 5; t++) {
    const int kb = q0 - 256 + 64 * t;
    __syncthreads();
    {
      const int key = tid >> 2, dimb = (tid & 3) * 32;
      const ushort_t* kgh = Kh + ((size_t)(b * S_ + kb + key) * D_) + h * HD_ + dimb;
#pragma unroll
      for (int u = 0; u < 4; u++)
        *(uint4*)&Ksh[key][dimb + u * 8] = *(const uint4*)(kgh + u * 8);
      const int hd = tid >> 1, keyb = (tid & 1) * 32;
      const ushort_t* vg = Vt + ((size_t)(b * D_ + h * HD_ + hd) * S_) + kb + keyb;
#pragma unroll
      for (int u = 0; u < 4; u++)
        *(uint4*)&Vs[hd][keyb + u * 8] = *(const uint4*)(vg + u * 8);
    }
    __syncthreads();

    f32x4 sacc[4] = {};
#pragma unroll
    for (int kk = 0; kk < 4; kk++)
#pragma unroll
      for (int nt = 0; nt < 4; nt++) {
        s16x8 kfh = *(const s16x8*)&Ksh[nt * 16 + l16][kk * 32 + quad * 8];
        sacc[nt] = mfma_bf16(qh[kk], kfh, sacc[nt]);
        sacc[nt] = mfma_bf16(ql[kk], kfh, sacc[nt]);
      }

#pragma unroll
    for (int nt = 0; nt < 4; nt++) {
      const int j = kb + nt * 16 + l16;
      const bool amok = ams[64 * t + nt * 16 + l16] != 0;
#pragma unroll
      for (int r = 0; r < 4; r++) {
        const int iq = q0 + wave * 16 + quad * 4 + r;
        const bool ok = amok && (j <= iq) && (j > iq - WIN_);
        if (!ok) sacc[nt][r] = -3.0e38f;
      }
    }
    float mt[4];
#pragma unroll
    for (int r = 0; r < 4; r++) {
      mt[r] = fmaxf(fmaxf(sacc[0][r], sacc[1][r]), fmaxf(sacc[2][r], sacc[3][r]));
      mt[r] = fmaxf(mt[r], __shfl_xor(mt[r], 1));
      mt[r] = fmaxf(mt[r], __shfl_xor(mt[r], 2));
      mt[r] = fmaxf(mt[r], __shfl_xor(mt[r], 4));
      mt[r] = fmaxf(mt[r], __shfl_xor(mt[r], 8));
    }
    float alpha[4], lt[4];
#pragma unroll
    for (int r = 0; r < 4; r++) {
      float mnew = fmaxf(m_run[r], mt[r]);
      alpha[r] = __expf(m_run[r] - mnew);
      m_run[r] = mnew;
      lt[r] = 0.f;
#pragma unroll
      for (int nt = 0; nt < 4; nt++) {
        float s = sacc[nt][r];
        float p = (s > -1.0e30f) ? __expf(s - mnew) : 0.f;
        sacc[nt][r] = p;
        lt[r] += p;
      }
      lt[r] += __shfl_xor(lt[r], 1);
      lt[r] += __shfl_xor(lt[r], 2);
      lt[r] += __shfl_xor(lt[r], 4);
      lt[r] += __shfl_xor(lt[r], 8);
      l_run[r] = l_run[r] * alpha[r] + lt[r];
    }
#pragma unroll
    for (int o = 0; o < 8; o++)
#pragma unroll
      for (int r = 0; r < 4; r++) O[o][r] *= alpha[r];
#pragma unroll
    for (int nt = 0; nt < 4; nt++)
#pragma unroll
      for (int r = 0; r < 4; r++)
        ps[wave][quad * 4 + r][nt * 16 + l16] = f2b(sacc[nt][r]);
    __syncthreads();
#pragma unroll
    for (int kk2 = 0; kk2 < 2; kk2++) {
      s16x8 pf = *(const s16x8*)&ps[wave][l16][kk2 * 32 + quad * 8];
#pragma unroll
      for (int o = 0; o < 8; o++) {
        s16x8 vf = *(const s16x8*)&Vs[o * 16 + l16][kk2 * 32 + quad * 8];
        O[o] = mfma_bf16(pf, vf, O[o]);
      }
    }
  }
#pragma unroll
  for (int r = 0; r < 4; r++) l_run[r] = 1.0f / l_run[r];
#pragma unroll
  for (int o = 0; o < 8; o++)
#pragma unroll
    for (int r = 0; r < 4; r++) {
      int row = q0 + wave * 16 + quad * 4 + r;
      AO[((size_t)(b * S_ + row) * D_) + h * HD_ + o * 16 + l16] = f2b(O[o][r] * l_run[r]);
    }
}

extern "C" void kernel_launch(void* const* d_in, const int* in_sizes, int n_in,
                              void* d_out, int out_size, void* d_ws, size_t ws_size,
                              hipStream_t stream) {
  const float* hs    = (const float*)d_in[0];
  const int*   amask = (const int*)d_in[1];
  const float* Wq    = (const float*)d_in[2];
  const float* Wk    = (const float*)d_in[3];
  const float* Wv    = (const float*)d_in[4];
  const float* Wo    = (const float*)d_in[5];
  const float* bo    = (const float*)d_in[6];
  float* out = (float*)d_out;

  char* p = (char*)d_ws;
  ushort_t* hsHi = (ushort_t*)p; p += (size_t)16 << 20;
  ushort_t* hsLo = (ushort_t*)p; p += (size_t)16 << 20;
  ushort_t* WqTh = (ushort_t*)p; p += (size_t)8 << 20;
  ushort_t* WqTl = (ushort_t*)p; p += (size_t)8 << 20;
  ushort_t* WkTh = (ushort_t*)p; p += (size_t)8 << 20;
  ushort_t* WkTl = (ushort_t*)p; p += (size_t)8 << 20;  (void)WkTl;
  ushort_t* WvTh = (ushort_t*)p; p += (size_t)8 << 20;
  ushort_t* WoTh = (ushort_t*)p; p += (size_t)8 << 20;
  ushort_t* Qhb  = (ushort_t*)p; p += (size_t)16 << 20;
  ushort_t* Qlb  = (ushort_t*)p; p += (size_t)16 << 20;
  ushort_t* Khb  = (ushort_t*)p; p += (size_t)16 << 20;
  ushort_t* Vb   = (ushort_t*)p; p += (size_t)16 << 20;
  ushort_t* Vt   = (ushort_t*)p; p += (size_t)16 << 20;

  k_split<<<M_ * D_ / 1024, 256, 0, stream>>>(hs, hsHi, hsLo, M_ * D_);
  dim3 tb(32, 8), tg4(D_ / 32, D_ / 32, 4);
  k_transpose4<<<tg4, tb, 0, stream>>>(Wq, Wk, Wv, Wo, WqTh, WqTl, WkTh, nullptr, WvTh, WoTh);

  // fused QKV: grid (24,16) = 384 blocks; bx<8 Q (3 segs), <16 K (2), else V (1)
  dim3 gq(24, 16);
  k_qkv<<<gq, 512, 0, stream>>>(hsHi, hsLo, WqTh, WqTl, WkTh, WvTh, Qhb, Qlb, Khb, Vb);

  dim3 vg(D_ / 32, S_ / 32, B_);
  k_vtrans<<<vg, tb, 0, stream>>>(Vb, Vt);

  dim3 ag(S_ / 64, H_, B_);  // (32, 16, 2)
  k_fattn<<<ag, 256, 0, stream>>>(Qhb, Qlb, Khb, Vt, amask, hsHi /*AO*/);

  // O: plain, f32 + bias epilogue (R1 structure, 256x128 tile)
  dim3 gg(D_ / 128, M_ / 256);
  k_gemm8<1, 2><<<gg, 512, 0, stream>>>(hsHi /*AO*/, nullptr, nullptr, WoTh, nullptr,
                                        nullptr, nullptr, out, bo, M_, D_, D_);
}

// Round 4
// 428.187 us; speedup vs baseline: 1.1556x; 1.0305x over previous
//
#include <hip/hip_runtime.h>

#define B_   2
#define S_   2048
#define D_   2048
#define H_   16
#define HD_  128
#define WIN_ 256
#define M_   (B_ * S_)  // 4096

typedef float  f32x4  __attribute__((ext_vector_type(4)));
typedef short  s16x8  __attribute__((ext_vector_type(8)));
typedef __bf16 bf16x8 __attribute__((ext_vector_type(8)));
typedef unsigned short ushort_t;

__device__ inline unsigned short f2b(float f) {
  unsigned u = __builtin_bit_cast(unsigned, f);
  u += 0x7fffu + ((u >> 16) & 1u);  // RNE
  return (unsigned short)(u >> 16);
}
__device__ inline float b2f(unsigned short h) {
  unsigned u = ((unsigned)h) << 16;
  return __builtin_bit_cast(float, u);
}

// Hedged MFMA call: gfx950 builtin may take v8bf16 (upstream clang) or v8i16.
template <typename T>
__device__ auto mfma_impl(T a, T b, f32x4 c, int)
    -> decltype(__builtin_amdgcn_mfma_f32_16x16x32_bf16(a, b, c, 0, 0, 0)) {
  return __builtin_amdgcn_mfma_f32_16x16x32_bf16(a, b, c, 0, 0, 0);
}
template <typename T>
__device__ f32x4 mfma_impl(T a, T b, f32x4 c, long) {
  return __builtin_amdgcn_mfma_f32_16x16x32_bf16(
      __builtin_bit_cast(bf16x8, a), __builtin_bit_cast(bf16x8, b), c, 0, 0, 0);
}
__device__ inline f32x4 mfma_bf16(s16x8 a, s16x8 b, f32x4 c) {
  return mfma_impl(a, b, c, 0);
}

// ---- async global->LDS, 16B/lane. lds base must be wave-uniform; lane i lands at +i*16B.
#if defined(__has_builtin)
#if __has_builtin(__builtin_amdgcn_global_load_lds)
#define HAS_GLL 1
#endif
#endif
#ifndef HAS_GLL
#define HAS_GLL 0
#endif

__device__ inline void gl_lds16(const ushort_t* g, ushort_t* lds_wave_base) {
#if HAS_GLL
  __builtin_amdgcn_global_load_lds(
      (const __attribute__((address_space(1))) unsigned int*)g,
      (__attribute__((address_space(3))) unsigned int*)lds_wave_base, 16, 0, 0);
#else
  const int lane = threadIdx.x & 63;
  *(uint4*)(lds_wave_base + lane * 8) = *(const uint4*)g;
#endif
}

// ---------------- split f32 -> bf16 hi + lo ----------------
__global__ __launch_bounds__(256) void k_split(const float* __restrict__ x,
                                               ushort_t* __restrict__ hi,
                                               ushort_t* __restrict__ lo, int n) {
  int i = (blockIdx.x * 256 + threadIdx.x) * 4;
  if (i + 3 < n) {
    float4 v = *(const float4*)(x + i);
    ushort4 h, l;
    h.x = f2b(v.x); l.x = f2b(v.x - b2f(h.x));
    h.y = f2b(v.y); l.y = f2b(v.y - b2f(h.y));
    h.z = f2b(v.z); l.z = f2b(v.z - b2f(h.z));
    h.w = f2b(v.w); l.w = f2b(v.w - b2f(h.w));
    *(ushort4*)(hi + i) = h;
    *(ushort4*)(lo + i) = l;
  }
}

// ---------------- fused transpose + split of all 4 weights: z picks W ----------------
__global__ __launch_bounds__(256) void k_transpose4(const float* __restrict__ W0,
                                                    const float* __restrict__ W1,
                                                    const float* __restrict__ W2,
                                                    const float* __restrict__ W3,
                                                    ushort_t* __restrict__ T0h,
                                                    ushort_t* __restrict__ T0l,
                                                    ushort_t* __restrict__ T1h,
                                                    ushort_t* __restrict__ T1l,
                                                    ushort_t* __restrict__ T2h,
                                                    ushort_t* __restrict__ T3h) {
  __shared__ float t[32][33];
  const int z = blockIdx.z;
  const float* W = (z == 0) ? W0 : (z == 1) ? W1 : (z == 2) ? W2 : W3;
  ushort_t* Th = (z == 0) ? T0h : (z == 1) ? T1h : (z == 2) ? T2h : T3h;
  ushort_t* Tl = (z == 0) ? T0l : (z == 1) ? T1l : nullptr;
  int bx = blockIdx.x * 32, by = blockIdx.y * 32;
  int tx = threadIdx.x, ty = threadIdx.y;  // 32 x 8
#pragma unroll
  for (int r = 0; r < 32; r += 8)
    t[ty + r][tx] = W[(size_t)(by + ty + r) * D_ + bx + tx];
  __syncthreads();
#pragma unroll
  for (int r = 0; r < 32; r += 8) {
    float v = t[tx][ty + r];
    unsigned short h = f2b(v);
    Th[(size_t)(bx + ty + r) * D_ + by + tx] = h;
    if (Tl) Tl[(size_t)(bx + ty + r) * D_ + by + tx] = f2b(v - b2f(h));
  }
}

// ---------------- bf16 transpose for V: Vt[b*D + c][s] = Vb[b*S + s][c] ----------------
__global__ __launch_bounds__(256) void k_vtrans(const ushort_t* __restrict__ Vb,
                                                ushort_t* __restrict__ Vt) {
  __shared__ ushort_t t[32][33];
  int bx = blockIdx.x * 32, by = blockIdx.y * 32, b = blockIdx.z;
  int tx = threadIdx.x, ty = threadIdx.y;  // 32 x 8
#pragma unroll
  for (int r = 0; r < 32; r += 8)
    t[ty + r][tx] = Vb[((size_t)(b * S_ + by + ty + r)) * D_ + bx + tx];
  __syncthreads();
#pragma unroll
  for (int r = 0; r < 32; r += 8)
    Vt[((size_t)(b * D_ + bx + ty + r)) * S_ + by + tx] = t[tx][ty + r];
}

// ================= fused QKV GEMM: C = A[4096 x 2048*segs] * [Wq|Wk|Wv]^T =========
// 256x256 tile, BK=32, 512 thr = 8 waves (2M x 4N) -> per-wave 128x64 output.
// 4 rotating LDS buffers (128 KB): compute tile kt from buf[kt&3], stage tile kt+3
// into buf[(kt+3)&3] -- never the current/next/next-next buffer => race-free.
// R4: MINIMAL barrier set -- ONE s_barrier per K-tile (after vmcnt(8) at tile end).
// Correctness: staging target (kt+3)&3 == (kt-1)&3, whose readers all passed the
// end-of-tile-(kt-1) barrier before any wave entered tile kt; per-wave skew is
// bounded by one tile by the single barrier. vmcnt(8) at tile end => tile kt+1
// fully landed for ALL waves after the barrier (each wave drained its own
// contributions to <=8 outstanding = tiles kt+2,kt+3). lgkmcnt(0)+sched_barrier(0)
// per wave orders its own ds_reads vs MFMAs (rule #18). Removing the lockstep
// leading barriers lets wave A's MFMA cluster run under wave B's ds_reads
// (separate pipes, m114); setprio(1) biases the MFMA wave.
// Swizzle: 16B-slot s of row r holds global slot s^((r>>1)&3) (store via
// pre-swizzled global source; read via XOR'd constant offset) -- 2-way max, free.
// N-concat: bx<8 -> Q (3 K-segs: (Ah,Wh),(Al,Wh),(Ah,Wl)); bx<16 -> K (2); else V.

__device__ inline void stage32(const ushort_t* __restrict__ g, int rowbase,
                               ushort_t* ldsTile, int tid) {
  const int rr = tid >> 2;                               // row 0..127 in chunk
  const int gs = ((tid & 3) ^ ((rr >> 1) & 3)) * 8;      // swizzled source slot
  gl_lds16(g + (size_t)(rowbase + rr) * D_ + gs,
           ldsTile + rowbase * 32 + (tid >> 6) * 512);   // wave-uniform LDS base
}

__global__ __launch_bounds__(512) void k_qkv(
    const ushort_t* __restrict__ Ah, const ushort_t* __restrict__ Al,
    const ushort_t* __restrict__ WqH, const ushort_t* __restrict__ WqL,
    const ushort_t* __restrict__ WkH, const ushort_t* __restrict__ WvH,
    ushort_t* __restrict__ Qh, ushort_t* __restrict__ Ql,
    ushort_t* __restrict__ Ko, ushort_t* __restrict__ Vo) {
  __shared__ ushort_t As_[4][256 * 32];  // 64 KB
  __shared__ ushort_t Bs_[4][256 * 32];  // 64 KB
  const int tid = threadIdx.x;
  const int wave = tid >> 6, lane = tid & 63;
  const int quad = lane >> 4, l16 = lane & 15;

  // bijective remap: XCD g (= orig linear id % 8) owns new ids g*48..g*48+47
  // = 2 contiguous M-panels -> A fetched ~once per XCD, L2-resident.
  const int lid = blockIdx.y * 24 + blockIdx.x;
  const int nlid = (lid & 7) * 48 + (lid >> 3);
  const int bx = nlid % 24, by = nlid / 24;
  const int m0 = by * 256;
  const int wtype = bx >> 3;            // 0=Q 1=K 2=V
  const int n0 = (bx & 7) * 256;
  const int nseg = (wtype == 0) ? 3 : (wtype == 1) ? 2 : 1;
  const ushort_t* Bh0 = (wtype == 0) ? WqH : (wtype == 1) ? WkH : WvH;
  const int NT = nseg << 6;             // K-tiles of 32

  const int wrM = (wave >> 2) * 128;    // 0 or 128
  const int wcN = (wave & 3) * 64;      // 0,64,128,192
  const int koff = (quad ^ ((l16 >> 1) & 3)) * 8;  // per-thread constant read slot

  // ---- prologue: stage tiles 0,1,2 (segment 0) ----
  {
    const ushort_t* Ap = Ah + (size_t)m0 * D_;
    const ushort_t* Bp = Bh0 + (size_t)n0 * D_;
#pragma unroll
    for (int t = 0; t < 3; ++t) {
      stage32(Ap + t * 32, 0,   &As_[t][0], tid);
      stage32(Ap + t * 32, 128, &As_[t][0], tid);
      stage32(Bp + t * 32, 0,   &Bs_[t][0], tid);
      stage32(Bp + t * 32, 128, &Bs_[t][0], tid);
    }
  }
  asm volatile("s_waitcnt vmcnt(8)" ::: "memory");  // tile 0 landed
  __builtin_amdgcn_s_barrier();
  asm volatile("" ::: "memory");

  f32x4 acc[8][4] = {};
  for (int kt = 0; kt < NT; ++kt) {
    const int st = kt + 3;
    const bool doSt = (st < NT);
    const int cur = kt & 3, sb = st & 3;
    const ushort_t* At = &As_[cur][0];
    const ushort_t* Bt = &Bs_[cur][0];
    ushort_t* Ad = &As_[sb][0];
    ushort_t* Bd = &Bs_[sb][0];
    const ushort_t* Asrc = Ah;
    const ushort_t* Bsrc = Bh0;
    if (doSt) {
      const int sg = st >> 6, so = (st & 63) * 32;
      const ushort_t* Ab = (sg == 1) ? Al : Ah;          // segs: Ah, Al, Ah
      const ushort_t* Bb = (sg == 2) ? WqL : Bh0;        // segs: Wh, Wh, Wl(Q only)
      Asrc = Ab + (size_t)m0 * D_ + so;
      Bsrc = Bb + (size_t)n0 * D_ + so;
    }
    s16x8 bf[4];
    // ---------- phase 0: rows wrM..wrM+63 (no barrier) ----------
    {
      s16x8 af[4];
#pragma unroll
      for (int mt = 0; mt < 4; ++mt)
        af[mt] = *(const s16x8*)(At + (wrM + mt * 16 + l16) * 32 + koff);
#pragma unroll
      for (int nt = 0; nt < 4; ++nt)
        bf[nt] = *(const s16x8*)(Bt + (wcN + nt * 16 + l16) * 32 + koff);
      if (doSt) {
        stage32(Asrc, 0,   Ad, tid);
        stage32(Asrc, 128, Ad, tid);
      }
      asm volatile("s_waitcnt lgkmcnt(0)" ::: "memory");
      __builtin_amdgcn_sched_barrier(0);
      __builtin_amdgcn_s_setprio(1);
#pragma unroll
      for (int mt = 0; mt < 4; ++mt)
#pragma unroll
        for (int nt = 0; nt < 4; ++nt)
          acc[mt][nt] = mfma_bf16(af[mt], bf[nt], acc[mt][nt]);
      __builtin_amdgcn_s_setprio(0);
    }
    // ---------- phase 1: rows wrM+64..wrM+127; single tile-end barrier ----------
    {
      s16x8 af[4];
#pragma unroll
      for (int mt = 0; mt < 4; ++mt)
        af[mt] = *(const s16x8*)(At + (wrM + 64 + mt * 16 + l16) * 32 + koff);
      if (doSt) {
        stage32(Bsrc, 0,   Bd, tid);
        stage32(Bsrc, 128, Bd, tid);
      }
      asm volatile("s_waitcnt lgkmcnt(0)" ::: "memory");
      __builtin_amdgcn_sched_barrier(0);
      __builtin_amdgcn_s_setprio(1);
#pragma unroll
      for (int mt = 0; mt < 4; ++mt)
#pragma unroll
        for (int nt = 0; nt < 4; ++nt)
          acc[4 + mt][nt] = mfma_bf16(af[mt], bf[nt], acc[4 + mt][nt]);
      __builtin_amdgcn_s_setprio(0);
      if (doSt)              asm volatile("s_waitcnt vmcnt(8)" ::: "memory");
      else if (kt == NT - 3) asm volatile("s_waitcnt vmcnt(4)" ::: "memory");
      else if (kt == NT - 2) asm volatile("s_waitcnt vmcnt(0)" ::: "memory");
      __builtin_amdgcn_s_barrier();
      asm volatile("" ::: "memory");
    }
  }

  // ---- epilogue: wave writes its 128x64 sub-tile ----
#pragma unroll
  for (int a = 0; a < 8; ++a)
#pragma unroll
    for (int nt = 0; nt < 4; ++nt)
#pragma unroll
      for (int r = 0; r < 4; ++r) {
        const int row = m0 + wrM + a * 16 + quad * 4 + r;
        const int col = n0 + wcN + nt * 16 + l16;
        const float v = acc[a][nt][r];
        const size_t idx = (size_t)row * D_ + col;
        if (wtype == 0) {
          unsigned short h = f2b(v);
          Qh[idx] = h;
          Ql[idx] = f2b(v - b2f(h));
        } else if (wtype == 1) {
          Ko[idx] = f2b(v);
        } else {
          Vo[idx] = f2b(v);
        }
      }
}

// ================= O-projection GEMM (R1 rotation, R4 minimal barriers) =========
__device__ inline void stage_chunk(const ushort_t* __restrict__ gbase, int K,
                                   int rowbase, ushort_t* ldsTile, int tid) {
  const int rr = tid >> 3;                       // row within 64-row chunk
  const int gs = ((tid & 7) ^ (rr & 7)) * 8;     // swizzled source 16B-slot
  gl_lds16(gbase + (size_t)(rowbase + rr) * K + gs,
           ldsTile + rowbase * 64 + (tid >> 6) * 512);  // wave-uniform LDS base
}

template <int NSEG, int OUT>
__global__ __launch_bounds__(512) void k_gemm8(
    const ushort_t* __restrict__ A0, const ushort_t* __restrict__ A1,
    const ushort_t* __restrict__ A2, const ushort_t* __restrict__ B0,
    const ushort_t* __restrict__ B2, ushort_t* __restrict__ Co,
    ushort_t* __restrict__ Col, float* __restrict__ Cf,
    const float* __restrict__ bias, int M, int N, int K) {
  __shared__ ushort_t As_[3][256 * 64];  // 96 KB
  __shared__ ushort_t Bs_[3][128 * 64];  // 48 KB
  const int tid = threadIdx.x;
  const int wave = tid >> 6, lane = tid & 63;
  const int quad = lane >> 4, l16 = lane & 15;
  const int m0 = blockIdx.y * 256, n0 = blockIdx.x * 128;
  const int wrM = (wave >> 1) * 64;  // 0,64,128,192
  const int wcN = (wave & 1) * 64;   // 0,64
  const int aRowB = (wrM + l16) * 64;
  const int bRowB = (wcN + l16) * 64;
  int ks8[2];
  ks8[0] = ((0 + quad) ^ (l16 & 7)) * 8;
  ks8[1] = ((4 + quad) ^ (l16 & 7)) * 8;
  const int NT = NSEG * 32;

  {
    const ushort_t* Ab0 = A0 + (size_t)m0 * K;
    const ushort_t* Bb0 = B0 + (size_t)n0 * K;
#pragma unroll
    for (int t = 0; t < 2; ++t) {
      const ushort_t* Ab = Ab0 + t * 64;
      const ushort_t* Bb = Bb0 + t * 64;
      stage_chunk(Ab, K, 0,   &As_[t][0], tid);
      stage_chunk(Ab, K, 64,  &As_[t][0], tid);
      stage_chunk(Ab, K, 128, &As_[t][0], tid);
      stage_chunk(Ab, K, 192, &As_[t][0], tid);
      stage_chunk(Bb, K, 0,   &Bs_[t][0], tid);
      stage_chunk(Bb, K, 64,  &Bs_[t][0], tid);
    }
  }
  asm volatile("s_waitcnt vmcnt(6)" ::: "memory");
  __builtin_amdgcn_s_barrier();
  asm volatile("" ::: "memory");

  f32x4 acc[4][4] = {};
  int cur = 0;
  for (int kt = 0; kt < NT; ++kt) {
    const int st = kt + 2;
    const bool doStage = (st < NT);
    int sbuf = cur + 2; if (sbuf >= 3) sbuf -= 3;
    ushort_t* At  = &As_[cur][0];
    ushort_t* Bt  = &Bs_[cur][0];
    ushort_t* Ads = &As_[sbuf][0];
    ushort_t* Bds = &Bs_[sbuf][0];
    const ushort_t* Asb = A0;
    const ushort_t* Bsb = B0;
    if (doStage) {
      const int sg = st >> 5;
      const ushort_t* Ag = A0;
      const ushort_t* Bg = B0;
      if (NSEG >= 2 && sg == 1) Ag = A1;
      if (NSEG == 3 && sg == 2) { Ag = A2; Bg = B2; }
      Asb = Ag + (size_t)m0 * K + (size_t)(st & 31) * 64;
      Bsb = Bg + (size_t)n0 * K + (size_t)(st & 31) * 64;
    }
    s16x8 bf[4][2];
#pragma unroll
    for (int p = 0; p < 2; ++p) {
      s16x8 af[2][2];
#pragma unroll
      for (int i = 0; i < 2; ++i)
#pragma unroll
        for (int s = 0; s < 2; ++s)
          af[i][s] = *(const s16x8*)(At + aRowB + (p * 2 + i) * 1024 + ks8[s]);
      if (p == 0) {
#pragma unroll
        for (int nt = 0; nt < 4; ++nt)
#pragma unroll
          for (int s = 0; s < 2; ++s)
            bf[nt][s] = *(const s16x8*)(Bt + bRowB + nt * 1024 + ks8[s]);
      }
      if (doStage) {
        if (p == 0) {
          stage_chunk(Asb, K, 0,   Ads, tid);
          stage_chunk(Asb, K, 64,  Ads, tid);
          stage_chunk(Asb, K, 128, Ads, tid);
        } else {
          stage_chunk(Asb, K, 192, Ads, tid);
          stage_chunk(Bsb, K, 0,   Bds, tid);
          stage_chunk(Bsb, K, 64,  Bds, tid);
        }
      }
      asm volatile("s_waitcnt lgkmcnt(0)" ::: "memory");
      __builtin_amdgcn_sched_barrier(0);
      __builtin_amdgcn_s_setprio(1);
#pragma unroll
      for (int i = 0; i < 2; ++i)
#pragma unroll
        for (int nt = 0; nt < 4; ++nt)
#pragma unroll
          for (int s = 0; s < 2; ++s)
            acc[p * 2 + i][nt] = mfma_bf16(af[i][s], bf[nt][s], acc[p * 2 + i][nt]);
      __builtin_amdgcn_s_setprio(0);
      if (p == 1) {
        if (doStage) asm volatile("s_waitcnt vmcnt(6)" ::: "memory");
        else         asm volatile("s_waitcnt vmcnt(0)" ::: "memory");
        __builtin_amdgcn_s_barrier();
        asm volatile("" ::: "memory");
      }
    }
    cur = (cur == 2) ? 0 : cur + 1;
  }

#pragma unroll
  for (int mt = 0; mt < 4; ++mt)
#pragma unroll
    for (int nt = 0; nt < 4; ++nt)
#pragma unroll
      for (int r = 0; r < 4; ++r) {
        int row = m0 + wrM + mt * 16 + quad * 4 + r;
        int col = n0 + wcN + nt * 16 + l16;
        float v = acc[mt][nt][r];
        if (OUT == 2) {
          Cf[(size_t)row * N + col] = v + bias[col];
        } else if (OUT == 1) {
          unsigned short h = f2b(v);
          Co[(size_t)row * N + col]  = h;
          Col[(size_t)row * N + col] = f2b(v - b2f(h));
        } else {
          Co[(size_t)row * N + col] = f2b(v);
        }
      }
}

// ---------------- MFMA flash attention, 64-query tile per block ----------------
__global__ __launch_bounds__(256) void k_fattn(const ushort_t* __restrict__ Qh,
                                               const ushort_t* __restrict__ Ql,
                                               const ushort_t* __restrict__ Kh,
                                               const ushort_t* __restrict__ Vt,
                                               const int* __restrict__ amask,
                                               ushort_t* __restrict__ AO) {
  __shared__ ushort_t Ksh[64][136];
  __shared__ ushort_t Vs[128][72];
  __shared__ ushort_t ps[4][16][72];
  __shared__ int ams[320];
  const int tid = threadIdx.x;
  const int wave = tid >> 6, lane = tid & 63;
  const int quad = lane >> 4, l16 = lane & 15;
  const int qt = blockIdx.x, h = blockIdx.y, b = blockIdx.z;
  const int q0 = qt * 64;

  for (int x = tid; x < 320; x += 256) {
    int j = q0 - 256 + x;
    ams[x] = (j >= 0) ? amask[b * S_ + j] : 0;
  }

  const int qrowA = q0 + wave * 16 + l16;
  const ushort_t* qbh = Qh + ((size_t)(b * S_ + qrowA) * D_) + h * HD_;
  const ushort_t* qbl = Ql + ((size_t)(b * S_ + qrowA) * D_) + h * HD_;
  s16x8 qh[4], ql[4];
#pragma unroll
  for (int kk = 0; kk < 4; kk++) {
    qh[kk] = *(const s16x8*)(qbh + kk * 32 + quad * 8);
    ql[kk] = *(const s16x8*)(qbl + kk * 32 + quad * 8);
  }

  f32x4 O[8] = {};
  float m_run[4], l_run[4];
#pragma unroll
  for (int r = 0; r < 4; r++) { m_run[r] = -3.0e38f; l_run[r] = 0.f; }

  const int t0 = (qt < 4) ? (4 - qt) : 0;
  for (int t = t0; t < 5; t++) {
    const int kb = q0 - 256 + 64 * t;
    __syncthreads();
    {
      const int key = tid >> 2, dimb = (tid & 3) * 32;
      const ushort_t* kgh = Kh + ((size_t)(b * S_ + kb + key) * D_) + h * HD_ + dimb;
#pragma unroll
      for (int u = 0; u < 4; u++)
        *(uint4*)&Ksh[key][dimb + u * 8] = *(const uint4*)(kgh + u * 8);
      const int hd = tid >> 1, keyb = (tid & 1) * 32;
      const ushort_t* vg = Vt + ((size_t)(b * D_ + h * HD_ + hd) * S_) + kb + keyb;
#pragma unroll
      for (int u = 0; u < 4; u++)
        *(uint4*)&Vs[hd][keyb + u * 8] = *(const uint4*)(vg + u * 8);
    }
    __syncthreads();

    f32x4 sacc[4] = {};
#pragma unroll
    for (int kk = 0; kk < 4; kk++)
#pragma unroll
      for (int nt = 0; nt < 4; nt++) {
        s16x8 kfh = *(const s16x8*)&Ksh[nt * 16 + l16][kk * 32 + quad * 8];
        sacc[nt] = mfma_bf16(qh[kk], kfh, sacc[nt]);
        sacc[nt] = mfma_bf16(ql[kk], kfh, sacc[nt]);
      }

#pragma unroll
    for (int nt = 0; nt < 4; nt++) {
      const int j = kb + nt * 16 + l16;
      const bool amok = ams[64 * t + nt * 16 + l16] != 0;
#pragma unroll
      for (int r = 0; r < 4; r++) {
        const int iq = q0 + wave * 16 + quad * 4 + r;
        const bool ok = amok && (j <= iq) && (j > iq - WIN_);
        if (!ok) sacc[nt][r] = -3.0e38f;
      }
    }
    float mt[4];
#pragma unroll
    for (int r = 0; r < 4; r++) {
      mt[r] = fmaxf(fmaxf(sacc[0][r], sacc[1][r]), fmaxf(sacc[2][r], sacc[3][r]));
      mt[r] = fmaxf(mt[r], __shfl_xor(mt[r], 1));
      mt[r] = fmaxf(mt[r], __shfl_xor(mt[r], 2));
      mt[r] = fmaxf(mt[r], __shfl_xor(mt[r], 4));
      mt[r] = fmaxf(mt[r], __shfl_xor(mt[r], 8));
    }
    float alpha[4], lt[4];
#pragma unroll
    for (int r = 0; r < 4; r++) {
      float mnew = fmaxf(m_run[r], mt[r]);
      alpha[r] = __expf(m_run[r] - mnew);
      m_run[r] = mnew;
      lt[r] = 0.f;
#pragma unroll
      for (int nt = 0; nt < 4; nt++) {
        float s = sacc[nt][r];
        float p = (s > -1.0e30f) ? __expf(s - mnew) : 0.f;
        sacc[nt][r] = p;
        lt[r] += p;
      }
      lt[r] += __shfl_xor(lt[r], 1);
      lt[r] += __shfl_xor(lt[r], 2);
      lt[r] += __shfl_xor(lt[r], 4);
      lt[r] += __shfl_xor(lt[r], 8);
      l_run[r] = l_run[r] * alpha[r] + lt[r];
    }
#pragma unroll
    for (int o = 0; o < 8; o++)
#pragma unroll
      for (int r = 0; r < 4; r++) O[o][r] *= alpha[r];
#pragma unroll
    for (int nt = 0; nt < 4; nt++)
#pragma unroll
      for (int r = 0; r < 4; r++)
        ps[wave][quad * 4 + r][nt * 16 + l16] = f2b(sacc[nt][r]);
    __syncthreads();
#pragma unroll
    for (int kk2 = 0; kk2 < 2; kk2++) {
      s16x8 pf = *(const s16x8*)&ps[wave][l16][kk2 * 32 + quad * 8];
#pragma unroll
      for (int o = 0; o < 8; o++) {
        s16x8 vf = *(const s16x8*)&Vs[o * 16 + l16][kk2 * 32 + quad * 8];
        O[o] = mfma_bf16(pf, vf, O[o]);
      }
    }
  }
#pragma unroll
  for (int r = 0; r < 4; r++) l_run[r] = 1.0f / l_run[r];
#pragma unroll
  for (int o = 0; o < 8; o++)
#pragma unroll
    for (int r = 0; r < 4; r++) {
      int row = q0 + wave * 16 + quad * 4 + r;
      AO[((size_t)(b * S_ + row) * D_) + h * HD_ + o * 16 + l16] = f2b(O[o][r] * l_run[r]);
    }
}

extern "C" void kernel_launch(void* const* d_in, const int* in_sizes, int n_in,
                              void* d_out, int out_size, void* d_ws, size_t ws_size,
                              hipStream_t stream) {
  const float* hs    = (const float*)d_in[0];
  const int*   amask = (const int*)d_in[1];
  const float* Wq    = (const float*)d_in[2];
  const float* Wk    = (const float*)d_in[3];
  const float* Wv    = (const float*)d_in[4];
  const float* Wo    = (const float*)d_in[5];
  const float* bo    = (const float*)d_in[6];
  float* out = (float*)d_out;

  char* p = (char*)d_ws;
  ushort_t* hsHi = (ushort_t*)p; p += (size_t)16 << 20;
  ushort_t* hsLo = (ushort_t*)p; p += (size_t)16 << 20;
  ushort_t* WqTh = (ushort_t*)p; p += (size_t)8 << 20;
  ushort_t* WqTl = (ushort_t*)p; p += (size_t)8 << 20;
  ushort_t* WkTh = (ushort_t*)p; p += (size_t)8 << 20;
  ushort_t* WkTl = (ushort_t*)p; p += (size_t)8 << 20;  (void)WkTl;
  ushort_t* WvTh = (ushort_t*)p; p += (size_t)8 << 20;
  ushort_t* WoTh = (ushort_t*)p; p += (size_t)8 << 20;
  ushort_t* Qhb  = (ushort_t*)p; p += (size_t)16 << 20;
  ushort_t* Qlb  = (ushort_t*)p; p += (size_t)16 << 20;
  ushort_t* Khb  = (ushort_t*)p; p += (size_t)16 << 20;
  ushort_t* Vb   = (ushort_t*)p; p += (size_t)16 << 20;
  ushort_t* Vt   = (ushort_t*)p; p += (size_t)16 << 20;

  k_split<<<M_ * D_ / 1024, 256, 0, stream>>>(hs, hsHi, hsLo, M_ * D_);
  dim3 tb(32, 8), tg4(D_ / 32, D_ / 32, 4);
  k_transpose4<<<tg4, tb, 0, stream>>>(Wq, Wk, Wv, Wo, WqTh, WqTl, WkTh, nullptr, WvTh, WoTh);

  // fused QKV: grid (24,16) = 384 blocks; bx<8 Q (3 segs), <16 K (2), else V (1)
  dim3 gq(24, 16);
  k_qkv<<<gq, 512, 0, stream>>>(hsHi, hsLo, WqTh, WqTl, WkTh, WvTh, Qhb, Qlb, Khb, Vb);

  dim3 vg(D_ / 32, S_ / 32, B_);
  k_vtrans<<<vg, tb, 0, stream>>>(Vb, Vt);

  dim3 ag(S_ / 64, H_, B_);  // (32, 16, 2)
  k_fattn<<<ag, 256, 0, stream>>>(Qhb, Qlb, Khb, Vt, amask, hsHi /*AO*/);

  // O: plain, f32 + bias epilogue (256x128 tile)
  dim3 gg(D_ / 128, M_ / 256);
  k_gemm8<1, 2><<<gg, 512, 0, stream>>>(hsHi /*AO*/, nullptr, nullptr, WoTh, nullptr,
                                        nullptr, nullptr, out, bo, M_, D_, D_);
}